// Round 7
// baseline (226.102 us; speedup 1.0000x reference)
//
#include <hip/hip_runtime.h>
#include <hip/hip_bf16.h>
#include <stdint.h>

typedef __attribute__((ext_vector_type(8))) short short8;
typedef __attribute__((ext_vector_type(4))) short short4v;
typedef __attribute__((ext_vector_type(4))) float f32x4;
typedef __attribute__((ext_vector_type(4))) unsigned short us4;

#define B_ 4
#define N_ 2048
#define C_ 1024
#define H_ 16
#define D_ 64

__device__ __forceinline__ unsigned short f2bf(float f) {
  union { float f; unsigned u; } v; v.f = f;
  unsigned u = v.u;
  u += 0x7fffu + ((u >> 16) & 1u);
  return (unsigned short)(u >> 16);
}

// compiler-visible bf16 convert (RNE)
__device__ __forceinline__ unsigned short bfc(float f) {
  union { __hip_bfloat16 h; unsigned short u; } v;
  v.h = __float2bfloat16(f);
  return v.u;
}

__device__ __forceinline__ void glds16(const unsigned short* g, const unsigned short* l) {
  __builtin_amdgcn_global_load_lds(
      (const __attribute__((address_space(1))) void*)(uintptr_t)g,
      (__attribute__((address_space(3))) void*)(uintptr_t)l, 16, 0, 0);
}

__device__ __forceinline__ f32x4 mfma16(short8 a, short8 b, f32x4 c) {
  return __builtin_amdgcn_mfma_f32_16x16x32_bf16(a, b, c, 0, 0, 0);
}

// 16x16x16 bf16 MFMA: B-operand layout == C/D layout granularity, so the
// swapped-QK^T output fragment is directly the PV B-operand (lane-local).
#if __has_builtin(__builtin_amdgcn_mfma_f32_16x16x16bf16_1k)
__device__ __forceinline__ f32x4 mfma16b(short4v a, short4v b, f32x4 c) {
  return __builtin_amdgcn_mfma_f32_16x16x16bf16_1k(a, b, c, 0, 0, 0);
}
#else
__device__ __forceinline__ f32x4 mfma16b(short4v a, short4v b, f32x4 c) {
  asm volatile("v_mfma_f32_16x16x16_bf16 %0, %1, %2, %0\n\ts_nop 7\n\ts_nop 7"
               : "+v"(c) : "v"(a), "v"(b));
  return c;
}
#endif

// ---------------- prep: row std (ddof=1) -> xn bf16, x bf16 ----------------
__global__ __launch_bounds__(256) void prep_k(const float* __restrict__ x,
                                              const float* __restrict__ gamma,
                                              unsigned short* __restrict__ xn,
                                              unsigned short* __restrict__ xb) {
  const int row = blockIdx.x, t = threadIdx.x;
  const float4 v = ((const float4*)(x + (size_t)row * C_))[t];
  float s1 = v.x + v.y + v.z + v.w;
  float s2 = v.x * v.x + v.y * v.y + v.z * v.z + v.w * v.w;
#pragma unroll
  for (int off = 32; off > 0; off >>= 1) {
    s1 += __shfl_down(s1, off);
    s2 += __shfl_down(s2, off);
  }
  __shared__ float r1[4], r2[4];
  if ((t & 63) == 0) { r1[t >> 6] = s1; r2[t >> 6] = s2; }
  __syncthreads();
  s1 = r1[0] + r1[1] + r1[2] + r1[3];
  s2 = r2[0] + r2[1] + r2[2] + r2[3];
  const float var = (s2 - s1 * s1 * (1.0f / C_)) * (1.0f / (C_ - 1));
  const float rstd = 1.0f / (sqrtf(var) + 1e-7f);
  const float4 gv = ((const float4*)gamma)[t];
  us4 a, b;
  a.x = f2bf(v.x); a.y = f2bf(v.y); a.z = f2bf(v.z); a.w = f2bf(v.w);
  b.x = f2bf(v.x * rstd * gv.x); b.y = f2bf(v.y * rstd * gv.y);
  b.z = f2bf(v.z * rstd * gv.z); b.w = f2bf(v.w * rstd * gv.w);
  ((us4*)(xb + (size_t)row * C_))[t] = a;
  ((us4*)(xn + (size_t)row * C_))[t] = b;
}

// ---------------- fp32 -> bf16 cast ----------------
__global__ __launch_bounds__(256) void cast_k(const float* __restrict__ s,
                                              unsigned short* __restrict__ d, int n4) {
  const int i = blockIdx.x * 256 + threadIdx.x;
  if (i >= n4) return;
  const float4 v = ((const float4*)s)[i];
  us4 o; o.x = f2bf(v.x); o.y = f2bf(v.y); o.z = f2bf(v.z); o.w = f2bf(v.w);
  ((us4*)d)[i] = o;
}

// ---------------- V transpose: kvb[n][64+d] -> vtb[b][d][n%2048] ------------
__global__ __launch_bounds__(256) void vtrans_k(const unsigned short* __restrict__ kvb,
                                                unsigned short* __restrict__ vtb) {
  __shared__ unsigned short T[64][68];
  const int t = threadIdx.x, nt = blockIdx.x;
  const int r = t >> 2, c4 = t & 3;
  const unsigned short* src = kvb + (size_t)(nt * 64 + r) * 128 + 64 + c4 * 16;
  *(short8*)&T[r][c4 * 16] = *(const short8*)src;
  *(short8*)&T[r][c4 * 16 + 8] = *(const short8*)(src + 8);
  __syncthreads();
  const int d = t >> 2, nq = t & 3;
  const int b = nt >> 5, nn0 = (nt & 31) * 64 + nq * 16;
  unsigned short* dst = vtb + ((size_t)b * 64 + d) * 2048 + nn0;
  short8 o0, o1;
#pragma unroll
  for (int j = 0; j < 8; ++j) {
    o0[j] = (short)T[nq * 16 + j][d];
    o1[j] = (short)T[nq * 16 + 8 + j][d];
  }
  *(short8*)dst = o0;
  *(short8*)(dst + 8) = o1;
}

// ---------------- GEMM: C[M,N] = A[M,K] * Bw[N,K]^T ------------------------
template <int EPI>
__global__ __launch_bounds__(256, 2) void gemm_bt(const unsigned short* __restrict__ A,
                                                  const unsigned short* __restrict__ Bw,
                                                  void* __restrict__ Cout,
                                                  const float* __restrict__ colscale,
                                                  float uscale, int M, int N, int K) {
  __shared__ unsigned short At[128 * 32];
  __shared__ unsigned short Bt[128 * 32];
  const int t = threadIdx.x;
  const int w = t >> 6, l = t & 63;
  const int ql = l & 15, g = l >> 4;
  const int wr = (w >> 1) * 64, wc = (w & 1) * 64;
  const int m0 = blockIdx.y * 128, n0 = blockIdx.x * 128;

  const int pr0 = t >> 2, pb0 = t & 3;
  const int lb0 = pb0 ^ ((pr0 >> 1) & 3);
  const int pr1 = 64 + (t >> 2);
  const int lb1 = pb0 ^ ((pr1 >> 1) & 3);
  const unsigned short* Ab = A + (size_t)m0 * K;
  const unsigned short* Bb = Bw + (size_t)n0 * K;

  f32x4 acc[4][4];
#pragma unroll
  for (int i = 0; i < 4; ++i)
#pragma unroll
    for (int j = 0; j < 4; ++j) acc[i][j] = f32x4{0.f, 0.f, 0.f, 0.f};

  for (int k0 = 0; k0 < K; k0 += 32) {
    glds16(Ab + (size_t)pr0 * K + k0 + lb0 * 8, &At[w * 512]);
    glds16(Ab + (size_t)pr1 * K + k0 + lb1 * 8, &At[2048 + w * 512]);
    glds16(Bb + (size_t)pr0 * K + k0 + lb0 * 8, &Bt[w * 512]);
    glds16(Bb + (size_t)pr1 * K + k0 + lb1 * 8, &Bt[2048 + w * 512]);
    __syncthreads();
    short8 af[4], bfr[4];
#pragma unroll
    for (int i = 0; i < 4; ++i) {
      const int row = wr + i * 16 + ql;
      af[i] = *(const short8*)&At[row * 32 + ((g ^ ((row >> 1) & 3)) * 8)];
    }
#pragma unroll
    for (int i = 0; i < 4; ++i) {
      const int row = wc + i * 16 + ql;
      bfr[i] = *(const short8*)&Bt[row * 32 + ((g ^ ((row >> 1) & 3)) * 8)];
    }
#pragma unroll
    for (int mi = 0; mi < 4; ++mi)
#pragma unroll
      for (int ni = 0; ni < 4; ++ni)
        acc[mi][ni] = mfma16(af[mi], bfr[ni], acc[mi][ni]);
    __syncthreads();
  }

  if (EPI == 0) {
    unsigned short* C = (unsigned short*)Cout;
#pragma unroll
    for (int mi = 0; mi < 4; ++mi)
#pragma unroll
      for (int ni = 0; ni < 4; ++ni) {
        const int col = n0 + wc + ni * 16 + ql;
#pragma unroll
        for (int r = 0; r < 4; ++r) {
          const int row = m0 + wr + mi * 16 + g * 4 + r;
          C[(size_t)row * N + col] = f2bf(acc[mi][ni][r] * uscale);
        }
      }
  } else {
    float* C = (float*)Cout;
#pragma unroll
    for (int mi = 0; mi < 4; ++mi)
#pragma unroll
      for (int ni = 0; ni < 4; ++ni) {
        const int col = n0 + wc + ni * 16 + ql;
        const float cs = colscale[col];
#pragma unroll
        for (int r = 0; r < 4; ++r) {
          const int row = m0 + wr + mi * 16 + g * 4 + r;
          C[(size_t)row * N + col] = acc[mi][ni][r] * cs;
        }
      }
  }
}

// ---------------- flash attention (MQA) -------------------------------------
// block = (b, hd, 128 q); 4 waves x 32 q. KVBLK=64, double-buffered glds16
// staging (XOR-swizzled source), ONE barrier per tile. QK^T = 16x16x32; its
// output fragment (after exp2 + bf16 pack) feeds PV's 16x16x16 MFMAs directly
// as the B-operand (identical lane mapping) -> NO P LDS roundtrip. lsum is
// per-lane partial, reduced once after the loop; max reduce is vote-only on
// the fast path (shfl only when the defer-max window is exceeded).
__global__ __launch_bounds__(256, 4) void attn_k(const unsigned short* __restrict__ qb,
                                                 const unsigned short* __restrict__ kvb,
                                                 const unsigned short* __restrict__ vtb,
                                                 unsigned short* __restrict__ ao) {
  __shared__ unsigned short Kt[2][64 * 64];
  __shared__ unsigned short Vt[2][64 * 64];

  const int idx = blockIdx.x;
  const int qc = idx & 15, hd = (idx >> 4) & 15, b = idx >> 8;
  const int t = threadIdx.x, w = t >> 6, l = t & 63;
  const int ql = l & 15, g = l >> 4;
  const int q0 = qc * 128 + w * 32;

  // Q fragments (scale incl. log2e folded into the Q GEMM epilogue)
  const unsigned short* qbase = qb + (size_t)(b * N_ + q0) * C_ + hd * D_;
  short8 Qf[2][2];
#pragma unroll
  for (int qs = 0; qs < 2; ++qs)
#pragma unroll
    for (int h = 0; h < 2; ++h)
      Qf[qs][h] = *(const short8*)(qbase + (size_t)(16 * qs + ql) * C_ + 32 * h + 8 * g);

  const unsigned short* kvrow = kvb + (size_t)(b * N_) * 128;
  const unsigned short* vtrow = vtb + (size_t)b * 64 * 2048;
  const int sr = l >> 3;                 // sub-row within an 8-row stage slab
  const int blk = ((l & 7) ^ sr) << 3;   // pre-swizzled source block (shorts)
  const int row0 = 16 * w + sr;
  const int row1 = row0 + 8;
  const int sw = ql & 7;

  auto stage = [&](int bi, int kt) {
    glds16(kvrow + (size_t)(kt * 64 + row0) * 128 + blk, &Kt[bi][(2 * w) * 512]);
    glds16(kvrow + (size_t)(kt * 64 + row1) * 128 + blk, &Kt[bi][(2 * w + 1) * 512]);
    glds16(vtrow + (size_t)row0 * 2048 + kt * 64 + blk, &Vt[bi][(2 * w) * 512]);
    glds16(vtrow + (size_t)row1 * 2048 + kt * 64 + blk, &Vt[bi][(2 * w + 1) * 512]);
  };

  f32x4 o[2][4];
#pragma unroll
  for (int qs = 0; qs < 2; ++qs)
#pragma unroll
    for (int dt = 0; dt < 4; ++dt) o[qs][dt] = f32x4{0.f, 0.f, 0.f, 0.f};
  float m[2] = {-1e30f, -1e30f}, lsum[2] = {0.f, 0.f};

  auto tilec = [&](int bi) {
    short8 Kf[4][2];
#pragma unroll
    for (int c = 0; c < 4; ++c) {
      const int roff = (16 * c + ql) * 64;
      Kf[c][0] = *(const short8*)&Kt[bi][roff + ((g ^ sw) << 3)];
      Kf[c][1] = *(const short8*)&Kt[bi][roff + (((g + 4) ^ sw) << 3)];
    }
    short4v pa[2][4];
#pragma unroll
    for (int qs = 0; qs < 2; ++qs) {
      f32x4 s[4];
#pragma unroll
      for (int c = 0; c < 4; ++c) {
        f32x4 acc = {0.f, 0.f, 0.f, 0.f};
        acc = mfma16(Kf[c][0], Qf[qs][0], acc);
        acc = mfma16(Kf[c][1], Qf[qs][1], acc);
        s[c] = acc;
      }
      // per-lane max only; __all() does the cross-lane combine for the check
      float tm = fmaxf(fmaxf(s[0][0], s[0][1]), fmaxf(s[0][2], s[0][3]));
#pragma unroll
      for (int c = 1; c < 4; ++c)
        tm = fmaxf(tm, fmaxf(fmaxf(s[c][0], s[c][1]), fmaxf(s[c][2], s[c][3])));
      if (!__all(tm <= m[qs] + 8.0f)) {  // defer-max (T13); rare after tile 0
        float tmr = fmaxf(tm, __shfl_xor(tm, 16));
        tmr = fmaxf(tmr, __shfl_xor(tmr, 32));
        const float mn = fmaxf(m[qs], tmr);
        const float corr = __builtin_amdgcn_exp2f(m[qs] - mn);
        lsum[qs] *= corr;  // per-lane partial scales linearly
#pragma unroll
        for (int dt = 0; dt < 4; ++dt) o[qs][dt] *= corr;
        m[qs] = mn;
      }
      float ps = 0.f;
#pragma unroll
      for (int c = 0; c < 4; ++c) {
        const float p0 = __builtin_amdgcn_exp2f(s[c][0] - m[qs]);
        const float p1 = __builtin_amdgcn_exp2f(s[c][1] - m[qs]);
        const float p2 = __builtin_amdgcn_exp2f(s[c][2] - m[qs]);
        const float p3 = __builtin_amdgcn_exp2f(s[c][3] - m[qs]);
        ps += (p0 + p1) + (p2 + p3);
        short4v pv;
        pv[0] = (short)bfc(p0); pv[1] = (short)bfc(p1);
        pv[2] = (short)bfc(p2); pv[3] = (short)bfc(p3);
        pa[qs][c] = pv;
      }
      lsum[qs] += ps;  // per-lane partial; reduced across g after the loop
    }
    // PV: O^T[d][q] += V^T-frag (A) x P-frag (B), 16x16x16 per kv-16-block
#pragma unroll
    for (int dt = 0; dt < 4; ++dt) {
      const int vro = (16 * dt + ql) * 64 + 4 * (g & 1);
      short4v Vf[4];
#pragma unroll
      for (int c = 0; c < 4; ++c)
        Vf[c] = *(const short4v*)&Vt[bi][vro + (((2 * c + (g >> 1)) ^ sw) << 3)];
#pragma unroll
      for (int qs = 0; qs < 2; ++qs)
#pragma unroll
        for (int c = 0; c < 4; ++c)
          o[qs][dt] = mfma16b(Vf[c], pa[qs][c], o[qs][dt]);
    }
  };

  stage(0, 0);
  for (int kt = 0; kt < 32; kt += 2) {
    __syncthreads();          // buf0 staged; prev buf1 reads done
    stage(1, kt + 1);         // prefetch, drained at next barrier
    tilec(0);
    __syncthreads();          // buf1 staged; buf0 reads done
    if (kt + 2 < 32) stage(0, kt + 2);
    tilec(1);
  }

#pragma unroll
  for (int qs = 0; qs < 2; ++qs) {
    lsum[qs] += __shfl_xor(lsum[qs], 16);
    lsum[qs] += __shfl_xor(lsum[qs], 32);
  }

#pragma unroll
  for (int qs = 0; qs < 2; ++qs) {
    const float inv = 1.0f / lsum[qs];
    unsigned short* orow = ao + (size_t)(b * N_ + q0 + 16 * qs + ql) * C_ + hd * D_;
#pragma unroll
    for (int dt = 0; dt < 4; ++dt) {
      us4 st;
      st.x = bfc(o[qs][dt][0] * inv);
      st.y = bfc(o[qs][dt][1] * inv);
      st.z = bfc(o[qs][dt][2] * inv);
      st.w = bfc(o[qs][dt][3] * inv);
      *(us4*)(orow + dt * 16 + 4 * g) = st;
    }
  }
}

extern "C" void kernel_launch(void* const* d_in, const int* in_sizes, int n_in,
                              void* d_out, int out_size, void* d_ws, size_t ws_size,
                              hipStream_t stream) {
  const float* x = (const float*)d_in[0];
  const float* gamma = (const float*)d_in[1];
  const float* Wq = (const float*)d_in[2];
  const float* Wkv = (const float*)d_in[3];
  const float* Wo = (const float*)d_in[4];
  const float* ls = (const float*)d_in[5];
  float* out = (float*)d_out;

  unsigned short* ws = (unsigned short*)d_ws;
  const size_t R = (size_t)B_ * N_;  // 8192 rows
  unsigned short* xn = ws;                       // R*C
  unsigned short* xb = xn + R * C_;              // R*C
  unsigned short* qbuf = xb + R * C_;            // R*C
  unsigned short* kvb = qbuf + R * C_;           // R*128
  unsigned short* aob = kvb + R * 128;           // R*C
  unsigned short* wqb = aob + R * C_;            // C*C
  unsigned short* wkvb = wqb + (size_t)C_ * C_;  // 128*C
  unsigned short* wob = wkvb + (size_t)128 * C_; // C*C  (= round-1 footprint)
  // vtb ALIASES wqb: Wq-bf16 is dead after the Q-GEMM; vtrans fully rewrites
  // this region every call before attn reads it (graph-replay deterministic).
  unsigned short* vtb = wqb;                     // 4*64*2048 <= C*C

  prep_k<<<(int)R, 256, 0, stream>>>(x, gamma, xn, xb);
  cast_k<<<(C_ * C_ / 4) / 256, 256, 0, stream>>>(Wq, wqb, C_ * C_ / 4);
  cast_k<<<(128 * C_ / 4) / 256, 256, 0, stream>>>(Wkv, wkvb, 128 * C_ / 4);
  cast_k<<<(C_ * C_ / 4) / 256, 256, 0, stream>>>(Wo, wob, C_ * C_ / 4);

  // q = xn @ Wq^T; fold SCALE * log2(e) = 0.125 * 1.4426950408889634
  gemm_bt<0><<<dim3(C_ / 128, R / 128), 256, 0, stream>>>(xn, wqb, qbuf, nullptr,
                                                          0.18033688011112042f,
                                                          (int)R, C_, C_);
  // kv = x @ Wkv^T (RAW x per reference)
  gemm_bt<0><<<dim3(1, R / 128), 256, 0, stream>>>(xb, wkvb, kvb, nullptr, 1.0f,
                                                   (int)R, 128, C_);
  vtrans_k<<<(int)(R / 64), 256, 0, stream>>>(kvb, vtb);  // overwrites wqb (dead)
  attn_k<<<B_ * H_ * (N_ / 128), 256, 0, stream>>>(qbuf, kvb, vtb, aob);
  // out = (ao @ Wo^T) * ls_scale[col], fp32
  gemm_bt<1><<<dim3(C_ / 128, R / 128), 256, 0, stream>>>(aob, wob, out, ls, 1.0f,
                                                          (int)R, C_, C_);
}

// Round 8
// 197.972 us; speedup vs baseline: 1.1421x; 1.1421x over previous
//
#include <hip/hip_runtime.h>
#include <hip/hip_bf16.h>
#include <stdint.h>

typedef __attribute__((ext_vector_type(8))) short short8;
typedef __attribute__((ext_vector_type(4))) short short4v;
typedef __attribute__((ext_vector_type(4))) float f32x4;
typedef __attribute__((ext_vector_type(4))) unsigned short us4;

#define B_ 4
#define N_ 2048
#define C_ 1024
#define H_ 16
#define D_ 64

__device__ __forceinline__ unsigned short f2bf(float f) {
  union { float f; unsigned u; } v; v.f = f;
  unsigned u = v.u;
  u += 0x7fffu + ((u >> 16) & 1u);
  return (unsigned short)(u >> 16);
}

// compiler-visible bf16 convert (RNE)
__device__ __forceinline__ unsigned short bfc(float f) {
  union { __hip_bfloat16 h; unsigned short u; } v;
  v.h = __float2bfloat16(f);
  return v.u;
}

__device__ __forceinline__ void glds16(const unsigned short* g, const unsigned short* l) {
  __builtin_amdgcn_global_load_lds(
      (const __attribute__((address_space(1))) void*)(uintptr_t)g,
      (__attribute__((address_space(3))) void*)(uintptr_t)l, 16, 0, 0);
}

__device__ __forceinline__ f32x4 mfma16(short8 a, short8 b, f32x4 c) {
  return __builtin_amdgcn_mfma_f32_16x16x32_bf16(a, b, c, 0, 0, 0);
}

// 16x16x16 bf16 MFMA: B-operand layout == C/D layout granularity, so the
// swapped-QK^T output fragment is directly the PV B-operand (lane-local).
#if __has_builtin(__builtin_amdgcn_mfma_f32_16x16x16bf16_1k)
__device__ __forceinline__ f32x4 mfma16b(short4v a, short4v b, f32x4 c) {
  return __builtin_amdgcn_mfma_f32_16x16x16bf16_1k(a, b, c, 0, 0, 0);
}
#else
__device__ __forceinline__ f32x4 mfma16b(short4v a, short4v b, f32x4 c) {
  asm volatile("v_mfma_f32_16x16x16_bf16 %0, %1, %2, %0\n\ts_nop 7\n\ts_nop 7"
               : "+v"(c) : "v"(a), "v"(b));
  return c;
}
#endif

// ---------------- prep: row std (ddof=1) -> xn bf16, x bf16 ----------------
__global__ __launch_bounds__(256) void prep_k(const float* __restrict__ x,
                                              const float* __restrict__ gamma,
                                              unsigned short* __restrict__ xn,
                                              unsigned short* __restrict__ xb) {
  const int row = blockIdx.x, t = threadIdx.x;
  const float4 v = ((const float4*)(x + (size_t)row * C_))[t];
  float s1 = v.x + v.y + v.z + v.w;
  float s2 = v.x * v.x + v.y * v.y + v.z * v.z + v.w * v.w;
#pragma unroll
  for (int off = 32; off > 0; off >>= 1) {
    s1 += __shfl_down(s1, off);
    s2 += __shfl_down(s2, off);
  }
  __shared__ float r1[4], r2[4];
  if ((t & 63) == 0) { r1[t >> 6] = s1; r2[t >> 6] = s2; }
  __syncthreads();
  s1 = r1[0] + r1[1] + r1[2] + r1[3];
  s2 = r2[0] + r2[1] + r2[2] + r2[3];
  const float var = (s2 - s1 * s1 * (1.0f / C_)) * (1.0f / (C_ - 1));
  const float rstd = 1.0f / (sqrtf(var) + 1e-7f);
  const float4 gv = ((const float4*)gamma)[t];
  us4 a, b;
  a.x = f2bf(v.x); a.y = f2bf(v.y); a.z = f2bf(v.z); a.w = f2bf(v.w);
  b.x = f2bf(v.x * rstd * gv.x); b.y = f2bf(v.y * rstd * gv.y);
  b.z = f2bf(v.z * rstd * gv.z); b.w = f2bf(v.w * rstd * gv.w);
  ((us4*)(xb + (size_t)row * C_))[t] = a;
  ((us4*)(xn + (size_t)row * C_))[t] = b;
}

// ---------------- fp32 -> bf16 cast ----------------
__global__ __launch_bounds__(256) void cast_k(const float* __restrict__ s,
                                              unsigned short* __restrict__ d, int n4) {
  const int i = blockIdx.x * 256 + threadIdx.x;
  if (i >= n4) return;
  const float4 v = ((const float4*)s)[i];
  us4 o; o.x = f2bf(v.x); o.y = f2bf(v.y); o.z = f2bf(v.z); o.w = f2bf(v.w);
  ((us4*)d)[i] = o;
}

// ---------------- V transpose: kvb[n][64+d] -> vtb[b][d][n%2048] ------------
__global__ __launch_bounds__(256) void vtrans_k(const unsigned short* __restrict__ kvb,
                                                unsigned short* __restrict__ vtb) {
  __shared__ unsigned short T[64][68];
  const int t = threadIdx.x, nt = blockIdx.x;
  const int r = t >> 2, c4 = t & 3;
  const unsigned short* src = kvb + (size_t)(nt * 64 + r) * 128 + 64 + c4 * 16;
  *(short8*)&T[r][c4 * 16] = *(const short8*)src;
  *(short8*)&T[r][c4 * 16 + 8] = *(const short8*)(src + 8);
  __syncthreads();
  const int d = t >> 2, nq = t & 3;
  const int b = nt >> 5, nn0 = (nt & 31) * 64 + nq * 16;
  unsigned short* dst = vtb + ((size_t)b * 64 + d) * 2048 + nn0;
  short8 o0, o1;
#pragma unroll
  for (int j = 0; j < 8; ++j) {
    o0[j] = (short)T[nq * 16 + j][d];
    o1[j] = (short)T[nq * 16 + 8 + j][d];
  }
  *(short8*)dst = o0;
  *(short8*)(dst + 8) = o1;
}

// ---------------- GEMM: C[M,N] = A[M,K] * Bw[N,K]^T ------------------------
template <int EPI>
__global__ __launch_bounds__(256, 2) void gemm_bt(const unsigned short* __restrict__ A,
                                                  const unsigned short* __restrict__ Bw,
                                                  void* __restrict__ Cout,
                                                  const float* __restrict__ colscale,
                                                  float uscale, int M, int N, int K) {
  __shared__ unsigned short At[128 * 32];
  __shared__ unsigned short Bt[128 * 32];
  const int t = threadIdx.x;
  const int w = t >> 6, l = t & 63;
  const int ql = l & 15, g = l >> 4;
  const int wr = (w >> 1) * 64, wc = (w & 1) * 64;
  const int m0 = blockIdx.y * 128, n0 = blockIdx.x * 128;

  const int pr0 = t >> 2, pb0 = t & 3;
  const int lb0 = pb0 ^ ((pr0 >> 1) & 3);
  const int pr1 = 64 + (t >> 2);
  const int lb1 = pb0 ^ ((pr1 >> 1) & 3);
  const unsigned short* Ab = A + (size_t)m0 * K;
  const unsigned short* Bb = Bw + (size_t)n0 * K;

  f32x4 acc[4][4];
#pragma unroll
  for (int i = 0; i < 4; ++i)
#pragma unroll
    for (int j = 0; j < 4; ++j) acc[i][j] = f32x4{0.f, 0.f, 0.f, 0.f};

  for (int k0 = 0; k0 < K; k0 += 32) {
    glds16(Ab + (size_t)pr0 * K + k0 + lb0 * 8, &At[w * 512]);
    glds16(Ab + (size_t)pr1 * K + k0 + lb1 * 8, &At[2048 + w * 512]);
    glds16(Bb + (size_t)pr0 * K + k0 + lb0 * 8, &Bt[w * 512]);
    glds16(Bb + (size_t)pr1 * K + k0 + lb1 * 8, &Bt[2048 + w * 512]);
    __syncthreads();
    short8 af[4], bfr[4];
#pragma unroll
    for (int i = 0; i < 4; ++i) {
      const int row = wr + i * 16 + ql;
      af[i] = *(const short8*)&At[row * 32 + ((g ^ ((row >> 1) & 3)) * 8)];
    }
#pragma unroll
    for (int i = 0; i < 4; ++i) {
      const int row = wc + i * 16 + ql;
      bfr[i] = *(const short8*)&Bt[row * 32 + ((g ^ ((row >> 1) & 3)) * 8)];
    }
#pragma unroll
    for (int mi = 0; mi < 4; ++mi)
#pragma unroll
      for (int ni = 0; ni < 4; ++ni)
        acc[mi][ni] = mfma16(af[mi], bfr[ni], acc[mi][ni]);
    __syncthreads();
  }

  if (EPI == 0) {
    unsigned short* C = (unsigned short*)Cout;
#pragma unroll
    for (int mi = 0; mi < 4; ++mi)
#pragma unroll
      for (int ni = 0; ni < 4; ++ni) {
        const int col = n0 + wc + ni * 16 + ql;
#pragma unroll
        for (int r = 0; r < 4; ++r) {
          const int row = m0 + wr + mi * 16 + g * 4 + r;
          C[(size_t)row * N + col] = f2bf(acc[mi][ni][r] * uscale);
        }
      }
  } else {
    float* C = (float*)Cout;
#pragma unroll
    for (int mi = 0; mi < 4; ++mi)
#pragma unroll
      for (int ni = 0; ni < 4; ++ni) {
        const int col = n0 + wc + ni * 16 + ql;
        const float cs = colscale[col];
#pragma unroll
        for (int r = 0; r < 4; ++r) {
          const int row = m0 + wr + mi * 16 + g * 4 + r;
          C[(size_t)row * N + col] = acc[mi][ni][r] * cs;
        }
      }
  }
}

// ---------------- flash attention (MQA) -------------------------------------
// block = (b, hd, 128 q); 4 waves x 32 q. KVBLK=64, double-buffered glds16
// staging (XOR-swizzled source), ONE barrier per tile. QK^T = 16x16x32; its
// output fragment (after exp2 + bf16 pack) feeds PV's 16x16x16 MFMAs directly
// as the B-operand (identical lane mapping) -> NO P LDS roundtrip. lsum is
// per-lane partial, reduced once after the loop; max reduce is vote-only on
// the fast path. launch_bounds(256,3): (256,4)'s 128-VGPR cap caused 205 MB
// of scratch spill traffic in round 7 — cap ~170 fits the live state.
__global__ __launch_bounds__(256, 3) void attn_k(const unsigned short* __restrict__ qb,
                                                 const unsigned short* __restrict__ kvb,
                                                 const unsigned short* __restrict__ vtb,
                                                 unsigned short* __restrict__ ao) {
  __shared__ unsigned short Kt[2][64 * 64];
  __shared__ unsigned short Vt[2][64 * 64];

  const int idx = blockIdx.x;
  const int qc = idx & 15, hd = (idx >> 4) & 15, b = idx >> 8;
  const int t = threadIdx.x, w = t >> 6, l = t & 63;
  const int ql = l & 15, g = l >> 4;
  const int q0 = qc * 128 + w * 32;

  // Q fragments (scale incl. log2e folded into the Q GEMM epilogue)
  const unsigned short* qbase = qb + (size_t)(b * N_ + q0) * C_ + hd * D_;
  short8 Qf[2][2];
#pragma unroll
  for (int qs = 0; qs < 2; ++qs)
#pragma unroll
    for (int h = 0; h < 2; ++h)
      Qf[qs][h] = *(const short8*)(qbase + (size_t)(16 * qs + ql) * C_ + 32 * h + 8 * g);

  const unsigned short* kvrow = kvb + (size_t)(b * N_) * 128;
  const unsigned short* vtrow = vtb + (size_t)b * 64 * 2048;
  const int sr = l >> 3;                 // sub-row within an 8-row stage slab
  const int blk = ((l & 7) ^ sr) << 3;   // pre-swizzled source block (shorts)
  const int row0 = 16 * w + sr;
  const int row1 = row0 + 8;
  const int sw = ql & 7;

  auto stage = [&](int bi, int kt) {
    glds16(kvrow + (size_t)(kt * 64 + row0) * 128 + blk, &Kt[bi][(2 * w) * 512]);
    glds16(kvrow + (size_t)(kt * 64 + row1) * 128 + blk, &Kt[bi][(2 * w + 1) * 512]);
    glds16(vtrow + (size_t)row0 * 2048 + kt * 64 + blk, &Vt[bi][(2 * w) * 512]);
    glds16(vtrow + (size_t)row1 * 2048 + kt * 64 + blk, &Vt[bi][(2 * w + 1) * 512]);
  };

  f32x4 o[2][4];
#pragma unroll
  for (int qs = 0; qs < 2; ++qs)
#pragma unroll
    for (int dt = 0; dt < 4; ++dt) o[qs][dt] = f32x4{0.f, 0.f, 0.f, 0.f};
  float m[2] = {-1e30f, -1e30f}, lsum[2] = {0.f, 0.f};

  auto tilec = [&](int bi) {
    short8 Kf[4][2];
#pragma unroll
    for (int c = 0; c < 4; ++c) {
      const int roff = (16 * c + ql) * 64;
      Kf[c][0] = *(const short8*)&Kt[bi][roff + ((g ^ sw) << 3)];
      Kf[c][1] = *(const short8*)&Kt[bi][roff + (((g + 4) ^ sw) << 3)];
    }
    short4v pa[2][4];
#pragma unroll
    for (int qs = 0; qs < 2; ++qs) {
      f32x4 s[4];
#pragma unroll
      for (int c = 0; c < 4; ++c) {
        f32x4 acc = {0.f, 0.f, 0.f, 0.f};
        acc = mfma16(Kf[c][0], Qf[qs][0], acc);
        acc = mfma16(Kf[c][1], Qf[qs][1], acc);
        s[c] = acc;
      }
      // per-lane max only; __all() does the cross-lane combine for the check
      float tm = fmaxf(fmaxf(s[0][0], s[0][1]), fmaxf(s[0][2], s[0][3]));
#pragma unroll
      for (int c = 1; c < 4; ++c)
        tm = fmaxf(tm, fmaxf(fmaxf(s[c][0], s[c][1]), fmaxf(s[c][2], s[c][3])));
      if (!__all(tm <= m[qs] + 8.0f)) {  // defer-max (T13); rare after tile 0
        float tmr = fmaxf(tm, __shfl_xor(tm, 16));
        tmr = fmaxf(tmr, __shfl_xor(tmr, 32));
        const float mn = fmaxf(m[qs], tmr);
        const float corr = __builtin_amdgcn_exp2f(m[qs] - mn);
        lsum[qs] *= corr;  // per-lane partial scales linearly
#pragma unroll
        for (int dt = 0; dt < 4; ++dt) o[qs][dt] *= corr;
        m[qs] = mn;
      }
      float ps = 0.f;
#pragma unroll
      for (int c = 0; c < 4; ++c) {
        const float p0 = __builtin_amdgcn_exp2f(s[c][0] - m[qs]);
        const float p1 = __builtin_amdgcn_exp2f(s[c][1] - m[qs]);
        const float p2 = __builtin_amdgcn_exp2f(s[c][2] - m[qs]);
        const float p3 = __builtin_amdgcn_exp2f(s[c][3] - m[qs]);
        ps += (p0 + p1) + (p2 + p3);
        short4v pv;
        pv[0] = (short)bfc(p0); pv[1] = (short)bfc(p1);
        pv[2] = (short)bfc(p2); pv[3] = (short)bfc(p3);
        pa[qs][c] = pv;
      }
      lsum[qs] += ps;  // per-lane partial; reduced across g after the loop
    }
    // PV: O^T[d][q] += V^T-frag (A) x P-frag (B), 16x16x16 per kv-16-block
#pragma unroll
    for (int dt = 0; dt < 4; ++dt) {
      const int vro = (16 * dt + ql) * 64 + 4 * (g & 1);
      short4v Vf[4];
#pragma unroll
      for (int c = 0; c < 4; ++c)
        Vf[c] = *(const short4v*)&Vt[bi][vro + (((2 * c + (g >> 1)) ^ sw) << 3)];
#pragma unroll
      for (int qs = 0; qs < 2; ++qs)
#pragma unroll
        for (int c = 0; c < 4; ++c)
          o[qs][dt] = mfma16b(Vf[c], pa[qs][c], o[qs][dt]);
    }
  };

  stage(0, 0);
  for (int kt = 0; kt < 32; kt += 2) {
    __syncthreads();          // buf0 staged; prev buf1 reads done
    stage(1, kt + 1);         // prefetch, drained at next barrier
    tilec(0);
    __syncthreads();          // buf1 staged; buf0 reads done
    if (kt + 2 < 32) stage(0, kt + 2);
    tilec(1);
  }

#pragma unroll
  for (int qs = 0; qs < 2; ++qs) {
    lsum[qs] += __shfl_xor(lsum[qs], 16);
    lsum[qs] += __shfl_xor(lsum[qs], 32);
  }

#pragma unroll
  for (int qs = 0; qs < 2; ++qs) {
    const float inv = 1.0f / lsum[qs];
    unsigned short* orow = ao + (size_t)(b * N_ + q0 + 16 * qs + ql) * C_ + hd * D_;
#pragma unroll
    for (int dt = 0; dt < 4; ++dt) {
      us4 st;
      st.x = bfc(o[qs][dt][0] * inv);
      st.y = bfc(o[qs][dt][1] * inv);
      st.z = bfc(o[qs][dt][2] * inv);
      st.w = bfc(o[qs][dt][3] * inv);
      *(us4*)(orow + dt * 16 + 4 * g) = st;
    }
  }
}

extern "C" void kernel_launch(void* const* d_in, const int* in_sizes, int n_in,
                              void* d_out, int out_size, void* d_ws, size_t ws_size,
                              hipStream_t stream) {
  const float* x = (const float*)d_in[0];
  const float* gamma = (const float*)d_in[1];
  const float* Wq = (const float*)d_in[2];
  const float* Wkv = (const float*)d_in[3];
  const float* Wo = (const float*)d_in[4];
  const float* ls = (const float*)d_in[5];
  float* out = (float*)d_out;

  unsigned short* ws = (unsigned short*)d_ws;
  const size_t R = (size_t)B_ * N_;  // 8192 rows
  unsigned short* xn = ws;                       // R*C
  unsigned short* xb = xn + R * C_;              // R*C
  unsigned short* qbuf = xb + R * C_;            // R*C
  unsigned short* kvb = qbuf + R * C_;           // R*128
  unsigned short* aob = kvb + R * 128;           // R*C
  unsigned short* wqb = aob + R * C_;            // C*C
  unsigned short* wkvb = wqb + (size_t)C_ * C_;  // 128*C
  unsigned short* wob = wkvb + (size_t)128 * C_; // C*C  (= round-1 footprint)
  // vtb ALIASES wqb: Wq-bf16 is dead after the Q-GEMM; vtrans fully rewrites
  // this region every call before attn reads it (graph-replay deterministic).
  unsigned short* vtb = wqb;                     // 4*64*2048 <= C*C

  prep_k<<<(int)R, 256, 0, stream>>>(x, gamma, xn, xb);
  cast_k<<<(C_ * C_ / 4) / 256, 256, 0, stream>>>(Wq, wqb, C_ * C_ / 4);
  cast_k<<<(128 * C_ / 4) / 256, 256, 0, stream>>>(Wkv, wkvb, 128 * C_ / 4);
  cast_k<<<(C_ * C_ / 4) / 256, 256, 0, stream>>>(Wo, wob, C_ * C_ / 4);

  // q = xn @ Wq^T; fold SCALE * log2(e) = 0.125 * 1.4426950408889634
  gemm_bt<0><<<dim3(C_ / 128, R / 128), 256, 0, stream>>>(xn, wqb, qbuf, nullptr,
                                                          0.18033688011112042f,
                                                          (int)R, C_, C_);
  // kv = x @ Wkv^T (RAW x per reference)
  gemm_bt<0><<<dim3(1, R / 128), 256, 0, stream>>>(xb, wkvb, kvb, nullptr, 1.0f,
                                                   (int)R, 128, C_);
  vtrans_k<<<(int)(R / 64), 256, 0, stream>>>(kvb, vtb);  // overwrites wqb (dead)
  attn_k<<<B_ * H_ * (N_ / 128), 256, 0, stream>>>(qbuf, kvb, vtb, aob);
  // out = (ao @ Wo^T) * ls_scale[col], fp32
  gemm_bt<1><<<dim3(C_ / 128, R / 128), 256, 0, stream>>>(aob, wob, out, ls, 1.0f,
                                                          (int)R, C_, C_);
}

// Round 9
// 179.154 us; speedup vs baseline: 1.2621x; 1.1050x over previous
//
#include <hip/hip_runtime.h>
#include <hip/hip_bf16.h>
#include <stdint.h>

typedef __attribute__((ext_vector_type(8))) short short8;
typedef __attribute__((ext_vector_type(4))) short short4v;
typedef __attribute__((ext_vector_type(4))) float f32x4;
typedef __attribute__((ext_vector_type(4))) unsigned short us4;

#define B_ 4
#define N_ 2048
#define C_ 1024
#define H_ 16
#define D_ 64

__device__ __forceinline__ unsigned short f2bf(float f) {
  union { float f; unsigned u; } v; v.f = f;
  unsigned u = v.u;
  u += 0x7fffu + ((u >> 16) & 1u);
  return (unsigned short)(u >> 16);
}

// compiler-visible bf16 convert (RNE)
__device__ __forceinline__ unsigned short bfc(float f) {
  union { __hip_bfloat16 h; unsigned short u; } v;
  v.h = __float2bfloat16(f);
  return v.u;
}

__device__ __forceinline__ void glds16(const unsigned short* g, const unsigned short* l) {
  __builtin_amdgcn_global_load_lds(
      (const __attribute__((address_space(1))) void*)(uintptr_t)g,
      (__attribute__((address_space(3))) void*)(uintptr_t)l, 16, 0, 0);
}

__device__ __forceinline__ f32x4 mfma16(short8 a, short8 b, f32x4 c) {
  return __builtin_amdgcn_mfma_f32_16x16x32_bf16(a, b, c, 0, 0, 0);
}

// 16x16x16 bf16 MFMA: B-operand layout == C/D layout granularity, so the
// swapped-QK^T output fragment is directly the PV B-operand (lane-local).
#if __has_builtin(__builtin_amdgcn_mfma_f32_16x16x16bf16_1k)
__device__ __forceinline__ f32x4 mfma16b(short4v a, short4v b, f32x4 c) {
  return __builtin_amdgcn_mfma_f32_16x16x16bf16_1k(a, b, c, 0, 0, 0);
}
#else
__device__ __forceinline__ f32x4 mfma16b(short4v a, short4v b, f32x4 c) {
  asm volatile("v_mfma_f32_16x16x16_bf16 %0, %1, %2, %0\n\ts_nop 7\n\ts_nop 7"
               : "+v"(c) : "v"(a), "v"(b));
  return c;
}
#endif

// ---------------- prep: row std (ddof=1) -> xn bf16, x bf16 ----------------
__global__ __launch_bounds__(256) void prep_k(const float* __restrict__ x,
                                              const float* __restrict__ gamma,
                                              unsigned short* __restrict__ xn,
                                              unsigned short* __restrict__ xb) {
  const int row = blockIdx.x, t = threadIdx.x;
  const float4 v = ((const float4*)(x + (size_t)row * C_))[t];
  float s1 = v.x + v.y + v.z + v.w;
  float s2 = v.x * v.x + v.y * v.y + v.z * v.z + v.w * v.w;
#pragma unroll
  for (int off = 32; off > 0; off >>= 1) {
    s1 += __shfl_down(s1, off);
    s2 += __shfl_down(s2, off);
  }
  __shared__ float r1[4], r2[4];
  if ((t & 63) == 0) { r1[t >> 6] = s1; r2[t >> 6] = s2; }
  __syncthreads();
  s1 = r1[0] + r1[1] + r1[2] + r1[3];
  s2 = r2[0] + r2[1] + r2[2] + r2[3];
  const float var = (s2 - s1 * s1 * (1.0f / C_)) * (1.0f / (C_ - 1));
  const float rstd = 1.0f / (sqrtf(var) + 1e-7f);
  const float4 gv = ((const float4*)gamma)[t];
  us4 a, b;
  a.x = f2bf(v.x); a.y = f2bf(v.y); a.z = f2bf(v.z); a.w = f2bf(v.w);
  b.x = f2bf(v.x * rstd * gv.x); b.y = f2bf(v.y * rstd * gv.y);
  b.z = f2bf(v.z * rstd * gv.z); b.w = f2bf(v.w * rstd * gv.w);
  ((us4*)(xb + (size_t)row * C_))[t] = a;
  ((us4*)(xn + (size_t)row * C_))[t] = b;
}

// ---------------- merged fp32 -> bf16 weight cast (Wq | Wkv | Wo) ----------
__global__ __launch_bounds__(256) void castw_k(const float* __restrict__ wq,
                                               const float* __restrict__ wkv,
                                               const float* __restrict__ wo,
                                               unsigned short* __restrict__ dq,
                                               unsigned short* __restrict__ dkv,
                                               unsigned short* __restrict__ dwo) {
  const int i = blockIdx.x * 256 + threadIdx.x;  // float4 index, 557056 total
  const float* s;
  unsigned short* d;
  int j;
  if (i < 262144) { s = wq; d = dq; j = i; }
  else if (i < 294912) { s = wkv; d = dkv; j = i - 262144; }
  else { s = wo; d = dwo; j = i - 294912; }
  const float4 v = ((const float4*)s)[j];
  us4 o; o.x = f2bf(v.x); o.y = f2bf(v.y); o.z = f2bf(v.z); o.w = f2bf(v.w);
  ((us4*)d)[j] = o;
}

// ---------------- V transpose: kvb[n][64+d] -> vtb[b][d][n%2048] ------------
// 16B blocks of row d store their 8B halves SWAPPED when (d>>3)&1 — paired
// with the read key ((g&1)^((ql>>3)&1)) this makes attn's ds_read_b64 V-reads
// cover all 32 banks uniformly in each 16-lane phase (round-8: 8.4M conflicts).
__global__ __launch_bounds__(256) void vtrans_k(const unsigned short* __restrict__ kvb,
                                                unsigned short* __restrict__ vtb) {
  __shared__ unsigned short T[64][68];
  const int t = threadIdx.x, nt = blockIdx.x;
  const int r = t >> 2, c4 = t & 3;
  const unsigned short* src = kvb + (size_t)(nt * 64 + r) * 128 + 64 + c4 * 16;
  *(short8*)&T[r][c4 * 16] = *(const short8*)src;
  *(short8*)&T[r][c4 * 16 + 8] = *(const short8*)(src + 8);
  __syncthreads();
  const int d = t >> 2, nq = t & 3;
  const int b = nt >> 5, nn0 = (nt & 31) * 64 + nq * 16;
  unsigned short* dst = vtb + ((size_t)b * 64 + d) * 2048 + nn0;
  short8 o0, o1;
#pragma unroll
  for (int j = 0; j < 8; ++j) {
    o0[j] = (short)T[nq * 16 + j][d];
    o1[j] = (short)T[nq * 16 + 8 + j][d];
  }
  if ((d >> 3) & 1) {
    o0 = __builtin_shufflevector(o0, o0, 4, 5, 6, 7, 0, 1, 2, 3);
    o1 = __builtin_shufflevector(o1, o1, 4, 5, 6, 7, 0, 1, 2, 3);
  }
  *(short8*)dst = o0;
  *(short8*)(dst + 8) = o1;
}

// ---------------- merged Q + KV GEMM: grid (9, 64) --------------------------
// bx<8: q = xn @ Wq^T (N=1024 panel bx, scale=0.125*log2e). bx==8: kv = xb @
// Wkv^T (N=128). Merging fills CUs during the tiny KV GEMM (64 blocks alone).
__global__ __launch_bounds__(256, 2) void qkv_gemm(const unsigned short* __restrict__ xn,
                                                   const unsigned short* __restrict__ xb,
                                                   const unsigned short* __restrict__ wq,
                                                   const unsigned short* __restrict__ wkv,
                                                   unsigned short* __restrict__ qo,
                                                   unsigned short* __restrict__ kvo) {
  const bool iskv = (blockIdx.x == 8);
  const unsigned short* A = iskv ? xb : xn;
  const unsigned short* Bw = iskv ? wkv : wq;
  unsigned short* Cc = iskv ? kvo : qo;
  const int N = iskv ? 128 : 1024;
  const int n0 = iskv ? 0 : blockIdx.x * 128;
  const float uscale = iskv ? 1.0f : 0.18033688011112042f;  // 0.125*log2(e)
  const int K = 1024, m0 = blockIdx.y * 128;

  __shared__ unsigned short At[128 * 32];
  __shared__ unsigned short Bt[128 * 32];
  const int t = threadIdx.x;
  const int w = t >> 6, l = t & 63;
  const int ql = l & 15, g = l >> 4;
  const int wr = (w >> 1) * 64, wc = (w & 1) * 64;

  const int pr0 = t >> 2, pb0 = t & 3;
  const int lb0 = pb0 ^ ((pr0 >> 1) & 3);
  const int pr1 = 64 + (t >> 2);
  const int lb1 = pb0 ^ ((pr1 >> 1) & 3);
  const unsigned short* Ab = A + (size_t)m0 * K;
  const unsigned short* Bb = Bw + (size_t)n0 * K;

  f32x4 acc[4][4];
#pragma unroll
  for (int i = 0; i < 4; ++i)
#pragma unroll
    for (int j = 0; j < 4; ++j) acc[i][j] = f32x4{0.f, 0.f, 0.f, 0.f};

  for (int k0 = 0; k0 < K; k0 += 32) {
    glds16(Ab + (size_t)pr0 * K + k0 + lb0 * 8, &At[w * 512]);
    glds16(Ab + (size_t)pr1 * K + k0 + lb1 * 8, &At[2048 + w * 512]);
    glds16(Bb + (size_t)pr0 * K + k0 + lb0 * 8, &Bt[w * 512]);
    glds16(Bb + (size_t)pr1 * K + k0 + lb1 * 8, &Bt[2048 + w * 512]);
    __syncthreads();
    short8 af[4], bfr[4];
#pragma unroll
    for (int i = 0; i < 4; ++i) {
      const int row = wr + i * 16 + ql;
      af[i] = *(const short8*)&At[row * 32 + ((g ^ ((row >> 1) & 3)) * 8)];
    }
#pragma unroll
    for (int i = 0; i < 4; ++i) {
      const int row = wc + i * 16 + ql;
      bfr[i] = *(const short8*)&Bt[row * 32 + ((g ^ ((row >> 1) & 3)) * 8)];
    }
#pragma unroll
    for (int mi = 0; mi < 4; ++mi)
#pragma unroll
      for (int ni = 0; ni < 4; ++ni)
        acc[mi][ni] = mfma16(af[mi], bfr[ni], acc[mi][ni]);
    __syncthreads();
  }

#pragma unroll
  for (int mi = 0; mi < 4; ++mi)
#pragma unroll
    for (int ni = 0; ni < 4; ++ni) {
      const int col = n0 + wc + ni * 16 + ql;
#pragma unroll
      for (int r = 0; r < 4; ++r) {
        const int row = m0 + wr + mi * 16 + g * 4 + r;
        Cc[(size_t)row * N + col] = f2bf(acc[mi][ni][r] * uscale);
      }
    }
}

// ---------------- O GEMM: out[M,N] = A[M,K] * Bw[N,K]^T, *colscale, fp32 ----
__global__ __launch_bounds__(256, 2) void gemm_o(const unsigned short* __restrict__ A,
                                                 const unsigned short* __restrict__ Bw,
                                                 float* __restrict__ Cout,
                                                 const float* __restrict__ colscale,
                                                 int M, int N, int K) {
  __shared__ unsigned short At[128 * 32];
  __shared__ unsigned short Bt[128 * 32];
  const int t = threadIdx.x;
  const int w = t >> 6, l = t & 63;
  const int ql = l & 15, g = l >> 4;
  const int wr = (w >> 1) * 64, wc = (w & 1) * 64;
  const int m0 = blockIdx.y * 128, n0 = blockIdx.x * 128;

  const int pr0 = t >> 2, pb0 = t & 3;
  const int lb0 = pb0 ^ ((pr0 >> 1) & 3);
  const int pr1 = 64 + (t >> 2);
  const int lb1 = pb0 ^ ((pr1 >> 1) & 3);
  const unsigned short* Ab = A + (size_t)m0 * K;
  const unsigned short* Bb = Bw + (size_t)n0 * K;

  f32x4 acc[4][4];
#pragma unroll
  for (int i = 0; i < 4; ++i)
#pragma unroll
    for (int j = 0; j < 4; ++j) acc[i][j] = f32x4{0.f, 0.f, 0.f, 0.f};

  for (int k0 = 0; k0 < K; k0 += 32) {
    glds16(Ab + (size_t)pr0 * K + k0 + lb0 * 8, &At[w * 512]);
    glds16(Ab + (size_t)pr1 * K + k0 + lb1 * 8, &At[2048 + w * 512]);
    glds16(Bb + (size_t)pr0 * K + k0 + lb0 * 8, &Bt[w * 512]);
    glds16(Bb + (size_t)pr1 * K + k0 + lb1 * 8, &Bt[2048 + w * 512]);
    __syncthreads();
    short8 af[4], bfr[4];
#pragma unroll
    for (int i = 0; i < 4; ++i) {
      const int row = wr + i * 16 + ql;
      af[i] = *(const short8*)&At[row * 32 + ((g ^ ((row >> 1) & 3)) * 8)];
    }
#pragma unroll
    for (int i = 0; i < 4; ++i) {
      const int row = wc + i * 16 + ql;
      bfr[i] = *(const short8*)&Bt[row * 32 + ((g ^ ((row >> 1) & 3)) * 8)];
    }
#pragma unroll
    for (int mi = 0; mi < 4; ++mi)
#pragma unroll
      for (int ni = 0; ni < 4; ++ni)
        acc[mi][ni] = mfma16(af[mi], bfr[ni], acc[mi][ni]);
    __syncthreads();
  }

#pragma unroll
  for (int mi = 0; mi < 4; ++mi)
#pragma unroll
    for (int ni = 0; ni < 4; ++ni) {
      const int col = n0 + wc + ni * 16 + ql;
      const float cs = colscale[col];
#pragma unroll
      for (int r = 0; r < 4; ++r) {
        const int row = m0 + wr + mi * 16 + g * 4 + r;
        Cout[(size_t)row * N + col] = acc[mi][ni][r] * cs;
      }
    }
}

// ---------------- flash attention (MQA) -------------------------------------
// block = (b, hd, 128 q); 4 waves x 32 q. KVBLK=64, double-buffered glds16
// staging (XOR-swizzled source), ONE barrier per tile. QK^T = 16x16x32; its
// output fragment (after exp2 + bf16 pack) feeds PV's 16x16x16 MFMAs directly
// as the B-operand -> NO P LDS roundtrip. V b64 reads use the half-swap key
// matching vtrans's storage swap (bank-uniform). launch_bounds(256,3).
__global__ __launch_bounds__(256, 3) void attn_k(const unsigned short* __restrict__ qb,
                                                 const unsigned short* __restrict__ kvb,
                                                 const unsigned short* __restrict__ vtb,
                                                 unsigned short* __restrict__ ao) {
  __shared__ unsigned short Kt[2][64 * 64];
  __shared__ unsigned short Vt[2][64 * 64];

  const int idx = blockIdx.x;
  const int qc = idx & 15, hd = (idx >> 4) & 15, b = idx >> 8;
  const int t = threadIdx.x, w = t >> 6, l = t & 63;
  const int ql = l & 15, g = l >> 4;
  const int q0 = qc * 128 + w * 32;

  // Q fragments (scale incl. log2e folded into the Q GEMM epilogue)
  const unsigned short* qbase = qb + (size_t)(b * N_ + q0) * C_ + hd * D_;
  short8 Qf[2][2];
#pragma unroll
  for (int qs = 0; qs < 2; ++qs)
#pragma unroll
    for (int h = 0; h < 2; ++h)
      Qf[qs][h] = *(const short8*)(qbase + (size_t)(16 * qs + ql) * C_ + 32 * h + 8 * g);

  const unsigned short* kvrow = kvb + (size_t)(b * N_) * 128;
  const unsigned short* vtrow = vtb + (size_t)b * 64 * 2048;
  const int sr = l >> 3;                 // sub-row within an 8-row stage slab
  const int blk = ((l & 7) ^ sr) << 3;   // pre-swizzled source block (shorts)
  const int row0 = 16 * w + sr;
  const int row1 = row0 + 8;
  const int sw = ql & 7;
  const int hb = (ql >> 3) & 1;          // V half-swap read key

  auto stage = [&](int bi, int kt) {
    glds16(kvrow + (size_t)(kt * 64 + row0) * 128 + blk, &Kt[bi][(2 * w) * 512]);
    glds16(kvrow + (size_t)(kt * 64 + row1) * 128 + blk, &Kt[bi][(2 * w + 1) * 512]);
    glds16(vtrow + (size_t)row0 * 2048 + kt * 64 + blk, &Vt[bi][(2 * w) * 512]);
    glds16(vtrow + (size_t)row1 * 2048 + kt * 64 + blk, &Vt[bi][(2 * w + 1) * 512]);
  };

  f32x4 o[2][4];
#pragma unroll
  for (int qs = 0; qs < 2; ++qs)
#pragma unroll
    for (int dt = 0; dt < 4; ++dt) o[qs][dt] = f32x4{0.f, 0.f, 0.f, 0.f};
  float m[2] = {-1e30f, -1e30f}, lsum[2] = {0.f, 0.f};

  auto tilec = [&](int bi) {
    short8 Kf[4][2];
#pragma unroll
    for (int c = 0; c < 4; ++c) {
      const int roff = (16 * c + ql) * 64;
      Kf[c][0] = *(const short8*)&Kt[bi][roff + ((g ^ sw) << 3)];
      Kf[c][1] = *(const short8*)&Kt[bi][roff + (((g + 4) ^ sw) << 3)];
    }
    short4v pa[2][4];
#pragma unroll
    for (int qs = 0; qs < 2; ++qs) {
      f32x4 s[4];
#pragma unroll
      for (int c = 0; c < 4; ++c) {
        f32x4 acc = {0.f, 0.f, 0.f, 0.f};
        acc = mfma16(Kf[c][0], Qf[qs][0], acc);
        acc = mfma16(Kf[c][1], Qf[qs][1], acc);
        s[c] = acc;
      }
      // per-lane max only; __all() does the cross-lane combine for the check
      float tm = fmaxf(fmaxf(s[0][0], s[0][1]), fmaxf(s[0][2], s[0][3]));
#pragma unroll
      for (int c = 1; c < 4; ++c)
        tm = fmaxf(tm, fmaxf(fmaxf(s[c][0], s[c][1]), fmaxf(s[c][2], s[c][3])));
      if (!__all(tm <= m[qs] + 8.0f)) {  // defer-max (T13); rare after tile 0
        float tmr = fmaxf(tm, __shfl_xor(tm, 16));
        tmr = fmaxf(tmr, __shfl_xor(tmr, 32));
        const float mn = fmaxf(m[qs], tmr);
        const float corr = __builtin_amdgcn_exp2f(m[qs] - mn);
        lsum[qs] *= corr;  // per-lane partial scales linearly
#pragma unroll
        for (int dt = 0; dt < 4; ++dt) o[qs][dt] *= corr;
        m[qs] = mn;
      }
      float ps = 0.f;
#pragma unroll
      for (int c = 0; c < 4; ++c) {
        const float p0 = __builtin_amdgcn_exp2f(s[c][0] - m[qs]);
        const float p1 = __builtin_amdgcn_exp2f(s[c][1] - m[qs]);
        const float p2 = __builtin_amdgcn_exp2f(s[c][2] - m[qs]);
        const float p3 = __builtin_amdgcn_exp2f(s[c][3] - m[qs]);
        ps += (p0 + p1) + (p2 + p3);
        short4v pv;
        pv[0] = (short)bfc(p0); pv[1] = (short)bfc(p1);
        pv[2] = (short)bfc(p2); pv[3] = (short)bfc(p3);
        pa[qs][c] = pv;
      }
      lsum[qs] += ps;  // per-lane partial; reduced across g after the loop
    }
    // PV: O^T[d][q] += V^T-frag (A) x P-frag (B), 16x16x16 per kv-16-block
#pragma unroll
    for (int dt = 0; dt < 4; ++dt) {
      const int vro = (16 * dt + ql) * 64 + 4 * ((g & 1) ^ hb);
      short4v Vf[4];
#pragma unroll
      for (int c = 0; c < 4; ++c)
        Vf[c] = *(const short4v*)&Vt[bi][vro + (((2 * c + (g >> 1)) ^ sw) << 3)];
#pragma unroll
      for (int qs = 0; qs < 2; ++qs)
#pragma unroll
        for (int c = 0; c < 4; ++c)
          o[qs][dt] = mfma16b(Vf[c], pa[qs][c], o[qs][dt]);
    }
  };

  stage(0, 0);
  for (int kt = 0; kt < 32; kt += 2) {
    __syncthreads();          // buf0 staged; prev buf1 reads done
    stage(1, kt + 1);         // prefetch, drained at next barrier
    tilec(0);
    __syncthreads();          // buf1 staged; buf0 reads done
    if (kt + 2 < 32) stage(0, kt + 2);
    tilec(1);
  }

#pragma unroll
  for (int qs = 0; qs < 2; ++qs) {
    lsum[qs] += __shfl_xor(lsum[qs], 16);
    lsum[qs] += __shfl_xor(lsum[qs], 32);
  }

#pragma unroll
  for (int qs = 0; qs < 2; ++qs) {
    const float inv = 1.0f / lsum[qs];
    unsigned short* orow = ao + (size_t)(b * N_ + q0 + 16 * qs + ql) * C_ + hd * D_;
#pragma unroll
    for (int dt = 0; dt < 4; ++dt) {
      us4 st;
      st.x = bfc(o[qs][dt][0] * inv);
      st.y = bfc(o[qs][dt][1] * inv);
      st.z = bfc(o[qs][dt][2] * inv);
      st.w = bfc(o[qs][dt][3] * inv);
      *(us4*)(orow + dt * 16 + 4 * g) = st;
    }
  }
}

extern "C" void kernel_launch(void* const* d_in, const int* in_sizes, int n_in,
                              void* d_out, int out_size, void* d_ws, size_t ws_size,
                              hipStream_t stream) {
  const float* x = (const float*)d_in[0];
  const float* gamma = (const float*)d_in[1];
  const float* Wq = (const float*)d_in[2];
  const float* Wkv = (const float*)d_in[3];
  const float* Wo = (const float*)d_in[4];
  const float* ls = (const float*)d_in[5];
  float* out = (float*)d_out;

  unsigned short* ws = (unsigned short*)d_ws;
  const size_t R = (size_t)B_ * N_;  // 8192 rows
  unsigned short* xn = ws;                       // R*C
  unsigned short* xb = xn + R * C_;              // R*C
  unsigned short* qbuf = xb + R * C_;            // R*C
  unsigned short* kvb = qbuf + R * C_;           // R*128
  unsigned short* aob = kvb + R * 128;           // R*C
  unsigned short* wqb = aob + R * C_;            // C*C
  unsigned short* wkvb = wqb + (size_t)C_ * C_;  // 128*C
  unsigned short* wob = wkvb + (size_t)128 * C_; // C*C  (= round-1 footprint)
  // vtb ALIASES wqb: Wq-bf16 is dead after the Q-GEMM; vtrans fully rewrites
  // this region every call before attn reads it (graph-replay deterministic).
  unsigned short* vtb = wqb;                     // 4*64*2048 <= C*C

  prep_k<<<(int)R, 256, 0, stream>>>(x, gamma, xn, xb);
  castw_k<<<2176, 256, 0, stream>>>(Wq, Wkv, Wo, wqb, wkvb, wob);
  // q = xn @ Wq^T (panels bx<8, scale=0.125*log2e) ++ kv = xb @ Wkv^T (bx==8)
  qkv_gemm<<<dim3(9, R / 128), 256, 0, stream>>>(xn, xb, wqb, wkvb, qbuf, kvb);
  vtrans_k<<<(int)(R / 64), 256, 0, stream>>>(kvb, vtb);  // overwrites wqb (dead)
  attn_k<<<B_ * H_ * (N_ / 128), 256, 0, stream>>>(qbuf, kvb, vtb, aob);
  // out = (ao @ Wo^T) * ls_scale[col], fp32
  gemm_o<<<dim3(C_ / 128, R / 128), 256, 0, stream>>>(aob, wob, out, ls,
                                                      (int)R, C_, C_);
}